// Round 5
// baseline (887.549 us; speedup 1.0000x reference)
//
#include <hip/hip_runtime.h>
#include <stdint.h>
#include <stddef.h>

typedef __bf16 bf16;
typedef __bf16 bf16x8 __attribute__((ext_vector_type(8)));
typedef float f32x4 __attribute__((ext_vector_type(4)));

#define AST 264              // activation row stride in bf16 elems (528B, 16B aligned)
#define BNI 0.9999950000374996f   // 1/sqrt(1+1e-5)

__device__ __forceinline__ bf16 f2b(float f){
  unsigned int i = __builtin_bit_cast(unsigned int, f);
  unsigned int r = i + 0x7fffu + ((i >> 16) & 1u);
  unsigned short h = (unsigned short)(r >> 16);
  return __builtin_bit_cast(bf16, h);
}
__device__ __forceinline__ float b2f(bf16 x){
  unsigned short u = __builtin_bit_cast(unsigned short, x);
  union { unsigned int i; float f; } v; v.i = ((unsigned int)u) << 16; return v.f;
}
// load 8 consecutive fp32 from global, convert to bf16x8 (RNE)
__device__ __forceinline__ bf16x8 ld8f(const float* p){
  f32x4 a = *(const f32x4*)p;
  f32x4 b = *(const f32x4*)(p + 4);
  bf16x8 r;
  #pragma unroll
  for (int j = 0; j < 4; ++j){ r[j] = f2b(a[j]); r[4+j] = f2b(b[j]); }
  return r;
}

// Stage 16 output-rows (slab nt) of fp32 W[.][ldW] into LDS slab as bf16 (row stride AST).
__device__ __forceinline__ void stageW(bf16* dst, const float* W, int ldW, int colOff, int nt, int tid){
  #pragma unroll
  for (int it = 0; it < 2; ++it){
    int idx = tid + it*320;            // 512 8-elem chunks needed
    if (idx < 512){
      int n = idx >> 5, c = idx & 31;
      bf16x8 v = ld8f(W + (size_t)(nt*16 + n)*ldW + colOff + c*8);
      *(bf16x8*)&dst[n*AST + c*8] = v;
    }
  }
}

// One 256->256 layer, in-place on sAct (each wave reads/writes only its own 16 rows).
// out = f((act @ W[:, colOff:+256]^T [+ t2]) * scale + bias) [* mask]
template<int RELU, int MASK, int ADDT2>
__device__ __forceinline__ void layer256(
    bf16* sAct, bf16* sW, const float* sT2v, const float* sMaskF,
    const float* W, int ldW, int colOff,
    const float* gptr, const float* bptr,
    int w, int lane16, int q, int tid)
{
  const int rowBase = w*16;
  bf16x8 a[8];
  #pragma unroll
  for (int t = 0; t < 8; ++t)
    a[t] = *(const bf16x8*)&sAct[(rowBase + lane16)*AST + 32*t + 8*q];  // own rows only

  int rows[4]; int polys[4]; float mk[4];
  #pragma unroll
  for (int i = 0; i < 4; ++i){
    int r = rowBase + q*4 + i;
    rows[i] = r; polys[i] = r / 20;
    mk[i] = MASK ? sMaskF[r] : 1.0f;
  }

  for (int nt = 0; nt < 16; ++nt){
    stageW(sW, W, ldW, colOff, nt, tid);
    __syncthreads();                   // slab staged; prev slab's readers done (trailing sync)
    f32x4 acc = {0.f, 0.f, 0.f, 0.f};
    #pragma unroll
    for (int t = 0; t < 8; ++t){
      bf16x8 b = *(const bf16x8*)&sW[lane16*AST + 32*t + 8*q];
      acc = __builtin_amdgcn_mfma_f32_16x16x32_bf16(a[t], b, acc, 0, 0, 0);
    }
    int col = nt*16 + lane16;
    float s  = gptr ? (gptr[col] * BNI) : 1.0f;
    float bb = bptr[col];
    #pragma unroll
    for (int i = 0; i < 4; ++i){
      float v = acc[i];
      if (ADDT2) v += sT2v[polys[i]*256 + col];
      v = v*s + bb;
      if (RELU) v = fmaxf(v, 0.0f);
      if (MASK) v *= mk[i];
      sAct[rows[i]*AST + col] = f2b(v);
    }
    __syncthreads();                   // all reads of this slab done before next staging
  }
}

// max over the 20 mask-zeroed rows of each polyline -> sPool rows 0..3 (rows 4..15 stay zero)
__device__ __forceinline__ void poolMax(const bf16* sAct, bf16* sPool, int tid){
  #pragma unroll
  for (int it = 0; it < 4; ++it){
    int idx = tid + it*320;       // 1024 = 4 polylines x 256 cols
    if (idx < 1024){
      int poly = idx >> 8, col = idx & 255;
      float m = b2f(sAct[(poly*20)*AST + col]);
      for (int r = 1; r < 20; ++r) m = fmaxf(m, b2f(sAct[(poly*20 + r)*AST + col]));
      sPool[poly*AST + col] = f2b(m);
    }
  }
}

__global__ __launch_bounds__(320, 2)
void traj_kernel(const float* __restrict__ poly, const int* __restrict__ maskp,
                 const float* pre_w0, const float* pre_g0, const float* pre_b0,
                 const float* pre_w1, const float* pre_g1, const float* pre_b1,
                 const float* pre_w2, const float* pre_bias2,
                 const float* mlp_w0, const float* mlp_g0, const float* mlp_b0,
                 const float* mlp_w1, const float* mlp_g1, const float* mlp_b1,
                 const float* mlp_w2, const float* mlp_bias2,
                 const float* out_w0, const float* out_b0,
                 const float* out_w1, const float* out_b1,
                 float* __restrict__ outp)
{
  __shared__ __align__(16) bf16  sAct[80*AST];    // 42,240 B
  __shared__ __align__(16) bf16  sW[16*AST];      //  8,448 B: weight slab / y-tile
  __shared__ __align__(16) bf16  sPool[16*AST];   //  8,448 B: pooled A-tile, rows 4..15 zero
  __shared__ __align__(16) float sT2v[4*256];     //  4,096 B
  __shared__ __align__(16) float sMaskF[80];
  __shared__ __align__(16) float sValidF[4];

  const int tid = threadIdx.x;
  const int w = tid >> 6, L = tid & 63, lane16 = L & 15, q = L >> 4;
  const int rowBase = w*16;
  const int blk = blockIdx.x;

  // ---- phase 0: load fp32 input (80x32) + int32 mask; zero sPool ----
  {
    int row = tid >> 2, ch = tid & 3;
    bf16x8 v = ld8f(poly + (size_t)(blk*80 + row)*32 + ch*8);
    *(bf16x8*)&sAct[row*AST + ch*8] = v;
    if (tid < 80) sMaskF[tid] = (maskp[blk*80 + tid] != 0) ? 1.0f : 0.0f;
    bf16x8 z = {};
    #pragma unroll
    for (int it = 0; it < 2; ++it){
      int idx = tid + it*320;          // 528 chunks = 16 rows x 33 chunks (incl. pad)
      if (idx < 528) *(bf16x8*)&sPool[idx*8] = z;
    }
  }
  __syncthreads();
  if (tid < 4){
    float v = 0.0f;
    #pragma unroll
    for (int r = 0; r < 20; ++r) v = fmaxf(v, sMaskF[tid*20 + r]);
    sValidF[tid] = v;                  // read only in out1, many barriers later
  }

  // ---- pre0: K=32, one MFMA k-step, B direct from global (fp32 -> bf16) ----
  {
    bf16x8 a0 = *(const bf16x8*)&sAct[(rowBase + lane16)*AST + 8*q];
    #pragma unroll
    for (int nt = 0; nt < 16; ++nt){
      bf16x8 b = ld8f(pre_w0 + (size_t)(nt*16 + lane16)*32 + 8*q);
      f32x4 acc = {0.f, 0.f, 0.f, 0.f};
      acc = __builtin_amdgcn_mfma_f32_16x16x32_bf16(a0, b, acc, 0, 0, 0);
      int col = nt*16 + lane16;
      float s  = pre_g0[col] * BNI;
      float bb = pre_b0[col];
      #pragma unroll
      for (int i = 0; i < 4; ++i){
        float v = fmaxf(acc[i]*s + bb, 0.0f);
        sAct[(rowBase + q*4 + i)*AST + col] = f2b(v);   // own rows only
      }
    }
  }
  __syncthreads();

  // ---- pre1, pre2 (pre2: no relu, mask-zero) ----
  layer256<1,0,0>(sAct, sW, sT2v, sMaskF, pre_w1, 256, 0, pre_g1, pre_b1, w, lane16, q, tid);
  layer256<0,1,0>(sAct, sW, sT2v, sMaskF, pre_w2, 256, 0, nullptr, pre_bias2, w, lane16, q, tid);

  // ---- pool 1 -> sPool rows 0..3 ----
  poolMax(sAct, sPool, tid);
  __syncthreads();

  // ---- t2 = pooled @ W0b^T (B direct from global; nt split across waves) ----
  {
    bf16x8 pa[8];
    #pragma unroll
    for (int t = 0; t < 8; ++t) pa[t] = *(const bf16x8*)&sPool[lane16*AST + 32*t + 8*q];
    for (int nt = w; nt < 16; nt += 5){
      f32x4 acc = {0.f, 0.f, 0.f, 0.f};
      #pragma unroll
      for (int t = 0; t < 8; ++t){
        bf16x8 b = ld8f(mlp_w0 + (size_t)(nt*16 + lane16)*512 + 256 + 32*t + 8*q);
        acc = __builtin_amdgcn_mfma_f32_16x16x32_bf16(pa[t], b, acc, 0, 0, 0);
      }
      if (q == 0){
        int col = nt*16 + lane16;
        #pragma unroll
        for (int i = 0; i < 4; ++i) sT2v[i*256 + col] = acc[i];
      }
    }
  }
  __syncthreads();

  // ---- mlp0 (x-half staged; pooled-half via sT2v), mlp1, mlp2 ----
  layer256<1,0,1>(sAct, sW, sT2v, sMaskF, mlp_w0, 512, 0, mlp_g0, mlp_b0, w, lane16, q, tid);
  layer256<1,0,0>(sAct, sW, sT2v, sMaskF, mlp_w1, 256, 0, mlp_g1, mlp_b1, w, lane16, q, tid);
  layer256<0,1,0>(sAct, sW, sT2v, sMaskF, mlp_w2, 256, 0, nullptr, mlp_bias2, w, lane16, q, tid);

  // ---- pool 2 -> sPool rows 0..3 ----
  poolMax(sAct, sPool, tid);
  __syncthreads();

  // ---- out0: y = relu(buf @ out_w0^T + b0) -> sW rows 0..3; zero sW rows 4..15 ----
  {
    bf16x8 pa[8];
    #pragma unroll
    for (int t = 0; t < 8; ++t) pa[t] = *(const bf16x8*)&sPool[lane16*AST + 32*t + 8*q];
    bf16x8 z = {};
    #pragma unroll
    for (int it = 0; it < 2; ++it){
      int idx = tid + it*320;          // rows 4..15 = 384 chunks
      if (idx < 384){
        int n = 4 + (idx >> 5), c = idx & 31;
        *(bf16x8*)&sW[n*AST + c*8] = z;
      }
    }
    for (int nt = w; nt < 16; nt += 5){
      f32x4 acc = {0.f, 0.f, 0.f, 0.f};
      #pragma unroll
      for (int t = 0; t < 8; ++t){
        bf16x8 b = ld8f(out_w0 + (size_t)(nt*16 + lane16)*256 + 32*t + 8*q);
        acc = __builtin_amdgcn_mfma_f32_16x16x32_bf16(pa[t], b, acc, 0, 0, 0);
      }
      if (q == 0){
        int col = nt*16 + lane16;
        #pragma unroll
        for (int i = 0; i < 4; ++i){
          float v = fmaxf(acc[i] + out_b0[col], 0.0f);
          sW[i*AST + col] = f2b(v);
        }
      }
    }
  }
  __syncthreads();

  // ---- out1: z = (y @ out_w1^T + b1) * valid -> global (fp32) ----
  {
    bf16x8 ya[8];
    #pragma unroll
    for (int t = 0; t < 8; ++t) ya[t] = *(const bf16x8*)&sW[lane16*AST + 32*t + 8*q];
    for (int nt = w; nt < 16; nt += 5){
      f32x4 acc = {0.f, 0.f, 0.f, 0.f};
      #pragma unroll
      for (int t = 0; t < 8; ++t){
        bf16x8 b = ld8f(out_w1 + (size_t)(nt*16 + lane16)*256 + 32*t + 8*q);
        acc = __builtin_amdgcn_mfma_f32_16x16x32_bf16(ya[t], b, acc, 0, 0, 0);
      }
      if (q == 0){
        int col = nt*16 + lane16;
        #pragma unroll
        for (int i = 0; i < 4; ++i){
          float v = (acc[i] + out_b1[col]) * sValidF[i];
          outp[(size_t)(blk*4 + i)*256 + col] = v;   // fp32 store — output dtype per reference
        }
      }
    }
  }
}

extern "C" void kernel_launch(void* const* d_in, const int* in_sizes, int n_in,
                              void* d_out, int out_size, void* d_ws, size_t ws_size,
                              hipStream_t stream)
{
  const float* poly      = (const float*)d_in[0];
  const int*   maskp     = (const int*)  d_in[1];
  const float* pre_w0    = (const float*)d_in[2];
  const float* pre_g0    = (const float*)d_in[3];
  const float* pre_b0    = (const float*)d_in[4];
  const float* pre_w1    = (const float*)d_in[5];
  const float* pre_g1    = (const float*)d_in[6];
  const float* pre_b1    = (const float*)d_in[7];
  const float* pre_w2    = (const float*)d_in[8];
  const float* pre_bias2 = (const float*)d_in[9];
  const float* mlp_w0    = (const float*)d_in[10];
  const float* mlp_g0    = (const float*)d_in[11];
  const float* mlp_b0    = (const float*)d_in[12];
  const float* mlp_w1    = (const float*)d_in[13];
  const float* mlp_g1    = (const float*)d_in[14];
  const float* mlp_b1    = (const float*)d_in[15];
  const float* mlp_w2    = (const float*)d_in[16];
  const float* mlp_bias2 = (const float*)d_in[17];
  const float* out_w0    = (const float*)d_in[18];
  const float* out_b0    = (const float*)d_in[19];
  const float* out_w1    = (const float*)d_in[20];
  const float* out_b1    = (const float*)d_in[21];

  traj_kernel<<<dim3(2048), dim3(320), 0, stream>>>(
      poly, maskp,
      pre_w0, pre_g0, pre_b0, pre_w1, pre_g1, pre_b1, pre_w2, pre_bias2,
      mlp_w0, mlp_g0, mlp_b0, mlp_w1, mlp_g1, mlp_b1, mlp_w2, mlp_bias2,
      out_w0, out_b0, out_w1, out_b1,
      (float*)d_out);
}

// Round 6
// 570.841 us; speedup vs baseline: 1.5548x; 1.5548x over previous
//
#include <hip/hip_runtime.h>
#include <stdint.h>
#include <stddef.h>

typedef __bf16 bf16;
typedef __bf16 bf16x8 __attribute__((ext_vector_type(8)));
typedef float f32x4 __attribute__((ext_vector_type(4)));

#define AST 264              // LDS row stride in bf16 elems (528B: 16B-aligned, 4-bank row skew)
#define SLAB (16*AST)
#define BNI 0.9999950000374996f   // 1/sqrt(1+1e-5)

// ws layout (bf16 elems)
#define WS_PRE_W0 0
#define WS_PRE_W1 8192
#define WS_PRE_W2 73728
#define WS_MLP_W0 139264
#define WS_MLP_W1 270336
#define WS_MLP_W2 335872
#define WS_OUT_W0 401408
#define WS_OUT_W1 466944

__device__ __forceinline__ bf16 f2b(float f){
  unsigned int i = __builtin_bit_cast(unsigned int, f);
  unsigned int r = i + 0x7fffu + ((i >> 16) & 1u);
  unsigned short h = (unsigned short)(r >> 16);
  return __builtin_bit_cast(bf16, h);
}
__device__ __forceinline__ float b2f(bf16 x){
  unsigned short u = __builtin_bit_cast(unsigned short, x);
  union { unsigned int i; float f; } v; v.i = ((unsigned int)u) << 16; return v.f;
}
__device__ __forceinline__ bf16x8 ld8f(const float* p){
  f32x4 a = *(const f32x4*)p;
  f32x4 b = *(const f32x4*)(p + 4);
  bf16x8 r;
  #pragma unroll
  for (int j = 0; j < 4; ++j){ r[j] = f2b(a[j]); r[4+j] = f2b(b[j]); }
  return r;
}

// ---------------- prep: fp32 weights -> bf16 in ws ----------------
__global__ __launch_bounds__(256)
void prep_kernel(const float* s0, const float* s1, const float* s2, const float* s3,
                 const float* s4, const float* s5, const float* s6, const float* s7,
                 bf16* dst)
{
  const int offs[8] = {WS_PRE_W0, WS_PRE_W1, WS_PRE_W2, WS_MLP_W0,
                       WS_MLP_W1, WS_MLP_W2, WS_OUT_W0, WS_OUT_W1};
  const int sz[8]   = {8192, 65536, 65536, 131072, 65536, 65536, 65536, 65536};
  int r = blockIdx.y;
  const float* src = s0;
  if (r == 1) src = s1; else if (r == 2) src = s2; else if (r == 3) src = s3;
  else if (r == 4) src = s4; else if (r == 5) src = s5; else if (r == 6) src = s6;
  else if (r == 7) src = s7;
  int i = (blockIdx.x*256 + threadIdx.x)*8;
  if (i < sz[r]){
    bf16x8 v = ld8f(src + i);
    *(bf16x8*)&dst[offs[r] + i] = v;
  }
}

// ---------------- fused main kernel ----------------
// One 256->256 layer, in-place on sAct. Double-buffered 16-row weight slabs,
// one barrier per slab; stage loads issued before the MFMA block so vmcnt
// waits land after compute.
template<int RELU, int MASK, int ADDT2>
__device__ __forceinline__ void layer256(
    bf16* sAct, bf16* sWb, const float* sT2v, const float* sMaskF,
    const bf16* W, int ldW,
    const float* gptr, const float* bptr,
    int w, int lane16, int q, int tid)
{
  const int rowBase = w*16;
  bf16x8 a[8];
  #pragma unroll
  for (int t = 0; t < 8; ++t)
    a[t] = *(const bf16x8*)&sAct[(rowBase + lane16)*AST + 32*t + 8*q];  // own rows only

  int rows[4]; int polys[4]; float mk[4];
  #pragma unroll
  for (int i = 0; i < 4; ++i){
    int r = rowBase + q*4 + i;
    rows[i] = r; polys[i] = r / 20;
    mk[i] = MASK ? sMaskF[r] : 1.0f;
  }

  const int n0 = tid >> 5, c0 = tid & 31;      // chunk tid of 512 (16 rows x 32 chunks)
  const bool has1 = tid < 192;
  const int n1 = (tid + 320) >> 5, c1 = (tid + 320) & 31;

  // prestage slab 0 -> buf0
  {
    bf16x8 v0 = *(const bf16x8*)(W + (size_t)n0*ldW + c0*8);
    *(bf16x8*)&sWb[n0*AST + c0*8] = v0;
    if (has1){
      bf16x8 v1 = *(const bf16x8*)(W + (size_t)n1*ldW + c1*8);
      *(bf16x8*)&sWb[n1*AST + c1*8] = v1;
    }
  }
  __syncthreads();

  #pragma unroll 4
  for (int nt = 0; nt < 16; ++nt){
    const bf16* cur = sWb + (nt & 1)*SLAB;
    bf16* nxt = sWb + ((nt + 1) & 1)*SLAB;
    bf16x8 s0 = {}, s1 = {};
    if (nt < 15){                                   // issue next-slab loads NOW
      const bf16* Wn = W + (size_t)(nt + 1)*16*ldW;
      s0 = *(const bf16x8*)(Wn + (size_t)n0*ldW + c0*8);
      if (has1) s1 = *(const bf16x8*)(Wn + (size_t)n1*ldW + c1*8);
    }
    f32x4 acc = {0.f, 0.f, 0.f, 0.f};
    #pragma unroll
    for (int t = 0; t < 8; ++t){
      bf16x8 b = *(const bf16x8*)&cur[lane16*AST + 32*t + 8*q];
      acc = __builtin_amdgcn_mfma_f32_16x16x32_bf16(a[t], b, acc, 0, 0, 0);
    }
    if (nt < 15){                                   // commit after MFMAs (vmcnt waits here)
      *(bf16x8*)&nxt[n0*AST + c0*8] = s0;
      if (has1) *(bf16x8*)&nxt[n1*AST + c1*8] = s1;
    }
    int col = nt*16 + lane16;
    float s  = gptr ? (gptr[col] * BNI) : 1.0f;
    float bb = bptr[col];
    #pragma unroll
    for (int i = 0; i < 4; ++i){
      float v = acc[i];
      if (ADDT2) v += sT2v[polys[i]*256 + col];
      v = v*s + bb;
      if (RELU) v = fmaxf(v, 0.0f);
      if (MASK) v *= mk[i];
      sAct[rows[i]*AST + col] = f2b(v);
    }
    __syncthreads();   // next slab staged AND cur's readers done
  }
}

// vectorized max over 20 mask-zeroed rows -> sPool rows 0..3 (rows 4..15: garbage is
// harmless — MFMA D-row r depends only on A-row r, and rows 4..15 results are discarded)
__device__ __forceinline__ void poolMaxV(const bf16* sAct, bf16* sPool, int tid){
  if (tid < 128){
    int poly = tid >> 5, c = tid & 31;
    float m[8];
    bf16x8 v0 = *(const bf16x8*)&sAct[(poly*20)*AST + c*8];
    #pragma unroll
    for (int j = 0; j < 8; ++j) m[j] = b2f(v0[j]);
    #pragma unroll
    for (int r = 1; r < 20; ++r){
      bf16x8 v = *(const bf16x8*)&sAct[(poly*20 + r)*AST + c*8];
      #pragma unroll
      for (int j = 0; j < 8; ++j) m[j] = fmaxf(m[j], b2f(v[j]));
    }
    bf16x8 o;
    #pragma unroll
    for (int j = 0; j < 8; ++j) o[j] = f2b(m[j]);
    *(bf16x8*)&sPool[poly*AST + c*8] = o;
  }
}

__global__ __launch_bounds__(320, 2)
void traj_kernel(const float* __restrict__ poly, const int* __restrict__ maskp,
                 const float* pre_g0, const float* pre_b0,
                 const float* pre_g1, const float* pre_b1,
                 const float* pre_bias2,
                 const float* mlp_g0, const float* mlp_b0,
                 const float* mlp_g1, const float* mlp_b1,
                 const float* mlp_bias2,
                 const float* out_b0, const float* out_b1,
                 const bf16* __restrict__ ws,
                 float* __restrict__ outp)
{
  __shared__ __align__(16) bf16  sAct[80*AST];    // 42,240 B
  __shared__ __align__(16) bf16  sWb[2*SLAB];     // 16,896 B: slab dbuf; aliased by sPool/sY
  __shared__ __align__(16) float sT2v[4*256];     //  4,096 B
  __shared__ __align__(16) float sMaskF[80];
  __shared__ __align__(16) float sValidF[4];
  bf16* sPool = sWb + SLAB;                       // buf1 (rows 0..3 meaningful)
  bf16* sY    = sWb;                              // buf0 (rows 0..3 meaningful)

  const int tid = threadIdx.x;
  const int w = tid >> 6, L = tid & 63, lane16 = L & 15, q = L >> 4;
  const int rowBase = w*16;
  const int blk = blockIdx.x;

  const bf16* pw0b = ws + WS_PRE_W0;
  const bf16* pw1b = ws + WS_PRE_W1;
  const bf16* pw2b = ws + WS_PRE_W2;
  const bf16* mw0b = ws + WS_MLP_W0;
  const bf16* mw1b = ws + WS_MLP_W1;
  const bf16* mw2b = ws + WS_MLP_W2;
  const bf16* ow0b = ws + WS_OUT_W0;
  const bf16* ow1b = ws + WS_OUT_W1;

  // ---- phase 0: load fp32 input (80x32) + int32 mask ----
  {
    int row = tid >> 2, ch = tid & 3;
    bf16x8 v = ld8f(poly + (size_t)(blk*80 + row)*32 + ch*8);
    *(bf16x8*)&sAct[row*AST + ch*8] = v;
    if (tid < 80) sMaskF[tid] = (maskp[blk*80 + tid] != 0) ? 1.0f : 0.0f;
  }
  __syncthreads();
  if (tid < 4){
    float v = 0.0f;
    #pragma unroll
    for (int r = 0; r < 20; ++r) v = fmaxf(v, sMaskF[tid*20 + r]);
    sValidF[tid] = v;                  // consumed only in out1
  }

  // ---- pre0: K=32, one MFMA k-step, B direct from ws (bf16) ----
  {
    bf16x8 a0 = *(const bf16x8*)&sAct[(rowBase + lane16)*AST + 8*q];
    #pragma unroll
    for (int nt = 0; nt < 16; ++nt){
      bf16x8 b = *(const bf16x8*)(pw0b + (size_t)(nt*16 + lane16)*32 + 8*q);
      f32x4 acc = {0.f, 0.f, 0.f, 0.f};
      acc = __builtin_amdgcn_mfma_f32_16x16x32_bf16(a0, b, acc, 0, 0, 0);
      int col = nt*16 + lane16;
      float s  = pre_g0[col] * BNI;
      float bb = pre_b0[col];
      #pragma unroll
      for (int i = 0; i < 4; ++i){
        float v = fmaxf(acc[i]*s + bb, 0.0f);
        sAct[(rowBase + q*4 + i)*AST + col] = f2b(v);   // own rows only
      }
    }
  }
  __syncthreads();

  // ---- pre1, pre2 (pre2: no relu, mask-zero) ----
  layer256<1,0,0>(sAct, sWb, sT2v, sMaskF, pw1b, 256, pre_g1, pre_b1, w, lane16, q, tid);
  layer256<0,1,0>(sAct, sWb, sT2v, sMaskF, pw2b, 256, nullptr, pre_bias2, w, lane16, q, tid);

  // ---- pool 1 ----
  poolMaxV(sAct, sPool, tid);
  __syncthreads();

  // ---- t2 = pooled @ mlp_w0[:,256:]^T  (B direct from ws; nt split across waves) ----
  {
    bf16x8 pa[8];
    #pragma unroll
    for (int t = 0; t < 8; ++t) pa[t] = *(const bf16x8*)&sPool[lane16*AST + 32*t + 8*q];
    for (int nt = w; nt < 16; nt += 5){
      f32x4 acc = {0.f, 0.f, 0.f, 0.f};
      #pragma unroll
      for (int t = 0; t < 8; ++t){
        bf16x8 b = *(const bf16x8*)(mw0b + (size_t)(nt*16 + lane16)*512 + 256 + 32*t + 8*q);
        acc = __builtin_amdgcn_mfma_f32_16x16x32_bf16(pa[t], b, acc, 0, 0, 0);
      }
      if (q == 0){
        int col = nt*16 + lane16;
        #pragma unroll
        for (int i = 0; i < 4; ++i) sT2v[i*256 + col] = acc[i];
      }
    }
  }
  __syncthreads();

  // ---- mlp0 (x-half staged; pooled-half via sT2v), mlp1, mlp2 ----
  layer256<1,0,1>(sAct, sWb, sT2v, sMaskF, mw0b, 512, mlp_g0, mlp_b0, w, lane16, q, tid);
  layer256<1,0,0>(sAct, sWb, sT2v, sMaskF, mw1b, 256, mlp_g1, mlp_b1, w, lane16, q, tid);
  layer256<0,1,0>(sAct, sWb, sT2v, sMaskF, mw2b, 256, nullptr, mlp_bias2, w, lane16, q, tid);

  // ---- pool 2 ----
  poolMaxV(sAct, sPool, tid);
  __syncthreads();

  // ---- out0: y = relu(buf @ out_w0^T + b0) -> sY rows 0..3 ----
  {
    bf16x8 pa[8];
    #pragma unroll
    for (int t = 0; t < 8; ++t) pa[t] = *(const bf16x8*)&sPool[lane16*AST + 32*t + 8*q];
    for (int nt = w; nt < 16; nt += 5){
      f32x4 acc = {0.f, 0.f, 0.f, 0.f};
      #pragma unroll
      for (int t = 0; t < 8; ++t){
        bf16x8 b = *(const bf16x8*)(ow0b + (size_t)(nt*16 + lane16)*256 + 32*t + 8*q);
        acc = __builtin_amdgcn_mfma_f32_16x16x32_bf16(pa[t], b, acc, 0, 0, 0);
      }
      if (q == 0){
        int col = nt*16 + lane16;
        #pragma unroll
        for (int i = 0; i < 4; ++i){
          float v = fmaxf(acc[i] + out_b0[col], 0.0f);
          sY[i*AST + col] = f2b(v);
        }
      }
    }
  }
  __syncthreads();

  // ---- out1: z = (y @ out_w1^T + b1) * valid -> global (fp32) ----
  {
    bf16x8 ya[8];
    #pragma unroll
    for (int t = 0; t < 8; ++t) ya[t] = *(const bf16x8*)&sY[lane16*AST + 32*t + 8*q];
    for (int nt = w; nt < 16; nt += 5){
      f32x4 acc = {0.f, 0.f, 0.f, 0.f};
      #pragma unroll
      for (int t = 0; t < 8; ++t){
        bf16x8 b = *(const bf16x8*)(ow1b + (size_t)(nt*16 + lane16)*256 + 32*t + 8*q);
        acc = __builtin_amdgcn_mfma_f32_16x16x32_bf16(ya[t], b, acc, 0, 0, 0);
      }
      if (q == 0){
        int col = nt*16 + lane16;
        #pragma unroll
        for (int i = 0; i < 4; ++i){
          float v = (acc[i] + out_b1[col]) * sValidF[i];
          outp[(size_t)(blk*4 + i)*256 + col] = v;
        }
      }
    }
  }
}

extern "C" void kernel_launch(void* const* d_in, const int* in_sizes, int n_in,
                              void* d_out, int out_size, void* d_ws, size_t ws_size,
                              hipStream_t stream)
{
  const float* poly      = (const float*)d_in[0];
  const int*   maskp     = (const int*)  d_in[1];
  const float* pre_w0    = (const float*)d_in[2];
  const float* pre_g0    = (const float*)d_in[3];
  const float* pre_b0    = (const float*)d_in[4];
  const float* pre_w1    = (const float*)d_in[5];
  const float* pre_g1    = (const float*)d_in[6];
  const float* pre_b1    = (const float*)d_in[7];
  const float* pre_w2    = (const float*)d_in[8];
  const float* pre_bias2 = (const float*)d_in[9];
  const float* mlp_w0    = (const float*)d_in[10];
  const float* mlp_g0    = (const float*)d_in[11];
  const float* mlp_b0    = (const float*)d_in[12];
  const float* mlp_w1    = (const float*)d_in[13];
  const float* mlp_g1    = (const float*)d_in[14];
  const float* mlp_b1    = (const float*)d_in[15];
  const float* mlp_w2    = (const float*)d_in[16];
  const float* mlp_bias2 = (const float*)d_in[17];
  const float* out_w0    = (const float*)d_in[18];
  const float* out_b0    = (const float*)d_in[19];
  const float* out_w1    = (const float*)d_in[20];
  const float* out_b1    = (const float*)d_in[21];

  bf16* ws = (bf16*)d_ws;   // needs 532,480 bf16 = 1,064,960 B of ws_size

  prep_kernel<<<dim3(64, 8), dim3(256), 0, stream>>>(
      pre_w0, pre_w1, pre_w2, mlp_w0, mlp_w1, mlp_w2, out_w0, out_w1, ws);

  traj_kernel<<<dim3(2048), dim3(320), 0, stream>>>(
      poly, maskp,
      pre_g0, pre_b0, pre_g1, pre_b1, pre_bias2,
      mlp_g0, mlp_b0, mlp_g1, mlp_b1, mlp_bias2,
      out_b0, out_b1,
      ws, (float*)d_out);
}

// Round 7
// 557.181 us; speedup vs baseline: 1.5929x; 1.0245x over previous
//
#include <hip/hip_runtime.h>
#include <stdint.h>
#include <stddef.h>

typedef __bf16 bf16;
typedef __bf16 bf16x8 __attribute__((ext_vector_type(8)));
typedef float f32x4 __attribute__((ext_vector_type(4)));
typedef float f32x16 __attribute__((ext_vector_type(16)));

#define AST 264                  // LDS act row stride (528B: 16B-aligned, 4-bank skew)
#define BNI 0.9999950000374996f // 1/sqrt(1+1e-5)

// dynamic-LDS layout (bytes)
#define OFF_ACT   0
#define OFF_POOL  (160*AST*2)             // 84480
#define OFF_T2    (OFF_POOL + 32*AST*2)   // 101376
#define OFF_MASK  (OFF_T2 + 8*256*4)      // 109568
#define OFF_VALID (OFF_MASK + 160*4)      // 110208
#define LDS_TOTAL (OFF_VALID + 32)        // 110240

// ws layout (bf16 elems)
#define WS_PRE_W0 0
#define WS_PRE_W1 8192
#define WS_PRE_W2 73728
#define WS_MLP_W0 139264
#define WS_MLP_W1 270336
#define WS_MLP_W2 335872
#define WS_OUT_W0 401408
#define WS_OUT_W1 466944

__device__ __forceinline__ bf16 f2b(float f){
  unsigned int i = __builtin_bit_cast(unsigned int, f);
  unsigned int r = i + 0x7fffu + ((i >> 16) & 1u);
  unsigned short h = (unsigned short)(r >> 16);
  return __builtin_bit_cast(bf16, h);
}
__device__ __forceinline__ float b2f(bf16 x){
  unsigned short u = __builtin_bit_cast(unsigned short, x);
  union { unsigned int i; float f; } v; v.i = ((unsigned int)u) << 16; return v.f;
}
__device__ __forceinline__ bf16x8 ld8f(const float* p){
  f32x4 a = *(const f32x4*)p;
  f32x4 b = *(const f32x4*)(p + 4);
  bf16x8 r;
  #pragma unroll
  for (int j = 0; j < 4; ++j){ r[j] = f2b(a[j]); r[4+j] = f2b(b[j]); }
  return r;
}

// ---------------- prep: fp32 weights -> bf16 in ws ----------------
__global__ __launch_bounds__(256)
void prep_kernel(const float* s0, const float* s1, const float* s2, const float* s3,
                 const float* s4, const float* s5, const float* s6, const float* s7,
                 bf16* dst)
{
  const int offs[8] = {WS_PRE_W0, WS_PRE_W1, WS_PRE_W2, WS_MLP_W0,
                       WS_MLP_W1, WS_MLP_W2, WS_OUT_W0, WS_OUT_W1};
  const int sz[8]   = {8192, 65536, 65536, 131072, 65536, 65536, 65536, 65536};
  int r = blockIdx.y;
  const float* src = s0;
  if (r == 1) src = s1; else if (r == 2) src = s2; else if (r == 3) src = s3;
  else if (r == 4) src = s4; else if (r == 5) src = s5; else if (r == 6) src = s6;
  else if (r == 7) src = s7;
  int i = (blockIdx.x*256 + threadIdx.x)*8;
  if (i < sz[r]){
    bf16x8 v = ld8f(src + i);
    *(bf16x8*)&dst[offs[r] + i] = v;
  }
}

// ---------------- main kernel helpers ----------------
__device__ __forceinline__ void loadB16(bf16x8* B, const bf16* W, int ldW, int nt,
                                        int lane32, int hi){
  const bf16* p = W + (size_t)(nt*32 + lane32)*ldW + 8*hi;
  #pragma unroll
  for (int k = 0; k < 16; ++k) B[k] = *(const bf16x8*)(p + k*16);
}

// one 32-col output tile: 16 k-step MFMAs + epilogue -> sAct (own rows only)
template<int RELU, int MASK, int ADDT2>
__device__ __forceinline__ void doNT(int nt, const bf16x8* A, const bf16x8* B,
    bf16* sAct, const float* sT2v,
    const float* gptr, const float* bptr,
    const float* mk, const int* rr, const int* pp,
    int rowBase, int lane32)
{
  f32x16 acc = {};
  #pragma unroll
  for (int k = 0; k < 16; ++k)
    acc = __builtin_amdgcn_mfma_f32_32x32x16_bf16(A[k], B[k], acc, 0, 0, 0);
  int col = nt*32 + lane32;
  float s  = gptr ? (gptr[col]*BNI) : 1.0f;
  float bb = bptr[col];
  #pragma unroll
  for (int reg = 0; reg < 16; ++reg){
    float v = acc[reg];
    if (ADDT2) v += sT2v[pp[reg]*256 + col];
    v = v*s + bb;
    if (RELU) v = fmaxf(v, 0.0f);
    if (MASK) v *= mk[reg];
    sAct[(rowBase + rr[reg])*AST + col] = f2b(v);
  }
}

// barrier-free 256->256 layer, in-place on the wave's own 32 rows
template<int RELU, int MASK, int ADDT2>
__device__ __forceinline__ void layer256(
    bf16* sAct, const float* sT2v, const float* sMaskF,
    const bf16* W, int ldW, const float* gptr, const float* bptr,
    int rowBase, int lane32, int hi)
{
  bf16x8 A[16];
  #pragma unroll
  for (int k = 0; k < 16; ++k)
    A[k] = *(const bf16x8*)&sAct[(rowBase + lane32)*AST + k*16 + 8*hi];

  float mk[16]; int rr[16]; int pp[16];
  #pragma unroll
  for (int reg = 0; reg < 16; ++reg){
    int r = (reg & 3) + 8*(reg >> 2) + 4*hi;        // verified C/D row map (m74/m101)
    rr[reg] = r;
    pp[reg] = (rowBase + r)/20;
    mk[reg] = MASK ? sMaskF[rowBase + r] : 1.0f;
  }

  bf16x8 B0[16], B1[16];
  loadB16(B0, W, ldW, 0, lane32, hi);
  #pragma unroll
  for (int half = 0; half < 4; ++half){
    loadB16(B1, W, ldW, 2*half + 1, lane32, hi);
    doNT<RELU,MASK,ADDT2>(2*half, A, B0, sAct, sT2v, gptr, bptr, mk, rr, pp, rowBase, lane32);
    if (half < 3) loadB16(B0, W, ldW, 2*half + 2, lane32, hi);
    doNT<RELU,MASK,ADDT2>(2*half + 1, A, B1, sAct, sT2v, gptr, bptr, mk, rr, pp, rowBase, lane32);
  }
}

// max over 20 mask-zeroed rows per polyline -> sPool rows 0..7 (rows 8..31: stale/poison
// bytes are finite bf16 (0xAAAA ok); MFMA D-row r depends only on A-row r -> harmless)
__device__ __forceinline__ void poolMaxV(const bf16* sAct, bf16* sPool, int tid){
  if (tid < 256){
    int poly = tid >> 5, c = tid & 31;
    float m[8];
    bf16x8 v0 = *(const bf16x8*)&sAct[(poly*20)*AST + c*8];
    #pragma unroll
    for (int j = 0; j < 8; ++j) m[j] = b2f(v0[j]);
    #pragma unroll
    for (int r = 1; r < 20; ++r){
      bf16x8 v = *(const bf16x8*)&sAct[(poly*20 + r)*AST + c*8];
      #pragma unroll
      for (int j = 0; j < 8; ++j) m[j] = fmaxf(m[j], b2f(v[j]));
    }
    bf16x8 o;
    #pragma unroll
    for (int j = 0; j < 8; ++j) o[j] = f2b(m[j]);
    *(bf16x8*)&sPool[poly*AST + c*8] = o;
  }
}

__global__ __launch_bounds__(320, 1)
void traj_kernel(const float* __restrict__ poly, const int* __restrict__ maskp,
                 const float* pre_g0, const float* pre_b0,
                 const float* pre_g1, const float* pre_b1,
                 const float* pre_bias2,
                 const float* mlp_g0, const float* mlp_b0,
                 const float* mlp_g1, const float* mlp_b1,
                 const float* mlp_bias2,
                 const float* out_b0, const float* out_b1,
                 const bf16* __restrict__ ws,
                 float* __restrict__ outp)
{
  extern __shared__ char smem[];
  bf16*  sAct    = (bf16*)(smem + OFF_ACT);    // 160 x 264
  bf16*  sPool   = (bf16*)(smem + OFF_POOL);   // 32 x 264 A-tile (rows 0..7 valid)
  float* sT2v    = (float*)(smem + OFF_T2);    // 8 x 256
  float* sMaskF  = (float*)(smem + OFF_MASK);  // 160
  float* sValidF = (float*)(smem + OFF_VALID); // 8

  const int tid = threadIdx.x;
  const int w = tid >> 6, L = tid & 63, lane32 = L & 31, hi = L >> 5;
  const int rowBase = w*32;
  const int blk = blockIdx.x;

  const bf16* pw0b = ws + WS_PRE_W0;
  const bf16* pw1b = ws + WS_PRE_W1;
  const bf16* pw2b = ws + WS_PRE_W2;
  const bf16* mw0b = ws + WS_MLP_W0;
  const bf16* mw1b = ws + WS_MLP_W1;
  const bf16* mw2b = ws + WS_MLP_W2;
  const bf16* ow0b = ws + WS_OUT_W0;
  const bf16* ow1b = ws + WS_OUT_W1;

  // ---- phase 0: load fp32 input (160x32) + int32 mask ----
  {
    #pragma unroll
    for (int it = 0; it < 2; ++it){
      int idx = tid + it*320;                 // 640 chunks = 160 rows x 4
      int row = idx >> 2, ch = idx & 3;
      bf16x8 v = ld8f(poly + (size_t)(blk*160 + row)*32 + ch*8);
      *(bf16x8*)&sAct[row*AST + ch*8] = v;
    }
    if (tid < 160) sMaskF[tid] = (maskp[blk*160 + tid] != 0) ? 1.0f : 0.0f;
  }
  __syncthreads();                            // B1
  if (tid < 8){
    float v = 0.0f;
    #pragma unroll
    for (int r = 0; r < 20; ++r) v = fmaxf(v, sMaskF[tid*20 + r]);
    sValidF[tid] = v;                         // consumed in out1 (many barriers later)
  }

  int rr[16];
  #pragma unroll
  for (int reg = 0; reg < 16; ++reg) rr[reg] = (reg & 3) + 8*(reg >> 2) + 4*hi;

  // ---- pre0: K=32 (2 k-steps), B direct from ws ----
  {
    bf16x8 a0 = *(const bf16x8*)&sAct[(rowBase + lane32)*AST + 8*hi];
    bf16x8 a1 = *(const bf16x8*)&sAct[(rowBase + lane32)*AST + 16 + 8*hi];
    #pragma unroll
    for (int nt = 0; nt < 8; ++nt){
      const bf16* p = pw0b + (size_t)(nt*32 + lane32)*32 + 8*hi;
      bf16x8 b0 = *(const bf16x8*)p;
      bf16x8 b1 = *(const bf16x8*)(p + 16);
      f32x16 acc = {};
      acc = __builtin_amdgcn_mfma_f32_32x32x16_bf16(a0, b0, acc, 0, 0, 0);
      acc = __builtin_amdgcn_mfma_f32_32x32x16_bf16(a1, b1, acc, 0, 0, 0);
      int col = nt*32 + lane32;
      float s = pre_g0[col]*BNI, bb = pre_b0[col];
      #pragma unroll
      for (int reg = 0; reg < 16; ++reg){
        float v = fmaxf(acc[reg]*s + bb, 0.0f);
        sAct[(rowBase + rr[reg])*AST + col] = f2b(v);
      }
    }
  }

  // ---- pre1, pre2 (barrier-free, own rows) ----
  layer256<1,0,0>(sAct, sT2v, sMaskF, pw1b, 256, pre_g1, pre_b1, rowBase, lane32, hi);
  layer256<0,1,0>(sAct, sT2v, sMaskF, pw2b, 256, nullptr, pre_bias2, rowBase, lane32, hi);

  __syncthreads();                            // B2: all pre2 writes done
  poolMaxV(sAct, sPool, tid);
  __syncthreads();                            // B3: pool1 visible

  // ---- t2 = pooled @ mlp_w0[:,256:]^T ----
  {
    bf16x8 A[16];
    #pragma unroll
    for (int k = 0; k < 16; ++k)
      A[k] = *(const bf16x8*)&sPool[lane32*AST + k*16 + 8*hi];
    for (int nt = w; nt < 8; nt += 5){
      const bf16* p = mw0b + (size_t)(nt*32 + lane32)*512 + 256 + 8*hi;
      f32x16 acc = {};
      #pragma unroll
      for (int k = 0; k < 16; ++k){
        bf16x8 b = *(const bf16x8*)(p + k*16);
        acc = __builtin_amdgcn_mfma_f32_32x32x16_bf16(A[k], b, acc, 0, 0, 0);
      }
      int col = nt*32 + lane32;
      #pragma unroll
      for (int reg = 0; reg < 4; ++reg)
        sT2v[(reg + 4*hi)*256 + col] = acc[reg];
    }
  }
  __syncthreads();                            // B4: sT2v ready

  // ---- mlp0 (x-half + t2), mlp1, mlp2 (barrier-free) ----
  layer256<1,0,1>(sAct, sT2v, sMaskF, mw0b, 512, mlp_g0, mlp_b0, rowBase, lane32, hi);
  layer256<1,0,0>(sAct, sT2v, sMaskF, mw1b, 256, mlp_g1, mlp_b1, rowBase, lane32, hi);
  layer256<0,1,0>(sAct, sT2v, sMaskF, mw2b, 256, nullptr, mlp_bias2, rowBase, lane32, hi);

  __syncthreads();                            // B5: all mlp2 writes done
  poolMaxV(sAct, sPool, tid);
  __syncthreads();                            // B6: pool2 visible

  // ---- out0: y = relu(buf @ out_w0^T + b0), held in regs across barrier ----
  float yv[2][4]; int myn[2]; int ncnt = 0;
  {
    bf16x8 A[16];
    #pragma unroll
    for (int k = 0; k < 16; ++k)
      A[k] = *(const bf16x8*)&sPool[lane32*AST + k*16 + 8*hi];
    for (int nt = w; nt < 8; nt += 5){
      const bf16* p = ow0b + (size_t)(nt*32 + lane32)*256 + 8*hi;
      f32x16 acc = {};
      #pragma unroll
      for (int k = 0; k < 16; ++k){
        bf16x8 b = *(const bf16x8*)(p + k*16);
        acc = __builtin_amdgcn_mfma_f32_32x32x16_bf16(A[k], b, acc, 0, 0, 0);
      }
      int col = nt*32 + lane32;
      #pragma unroll
      for (int reg = 0; reg < 4; ++reg)
        yv[ncnt][reg] = fmaxf(acc[reg] + out_b0[col], 0.0f);
      myn[ncnt++] = nt;
    }
  }
  __syncthreads();                            // B7: all pooled A-reads done
  for (int j = 0; j < ncnt; ++j){
    int col = myn[j]*32 + lane32;
    #pragma unroll
    for (int reg = 0; reg < 4; ++reg)
      sPool[(reg + 4*hi)*AST + col] = f2b(yv[j][reg]);
  }
  __syncthreads();                            // B8: y visible

  // ---- out1: z = (y @ out_w1^T + b1) * valid -> global fp32 ----
  {
    bf16x8 A[16];
    #pragma unroll
    for (int k = 0; k < 16; ++k)
      A[k] = *(const bf16x8*)&sPool[lane32*AST + k*16 + 8*hi];
    for (int nt = w; nt < 8; nt += 5){
      const bf16* p = ow1b + (size_t)(nt*32 + lane32)*256 + 8*hi;
      f32x16 acc = {};
      #pragma unroll
      for (int k = 0; k < 16; ++k){
        bf16x8 b = *(const bf16x8*)(p + k*16);
        acc = __builtin_amdgcn_mfma_f32_32x32x16_bf16(A[k], b, acc, 0, 0, 0);
      }
      int col = nt*32 + lane32;
      #pragma unroll
      for (int reg = 0; reg < 4; ++reg){
        int r = reg + 4*hi;
        outp[(size_t)(blk*8 + r)*256 + col] = (acc[reg] + out_b1[col]) * sValidF[r];
      }
    }
  }
}

extern "C" void kernel_launch(void* const* d_in, const int* in_sizes, int n_in,
                              void* d_out, int out_size, void* d_ws, size_t ws_size,
                              hipStream_t stream)
{
  const float* poly      = (const float*)d_in[0];
  const int*   maskp     = (const int*)  d_in[1];
  const float* pre_w0    = (const float*)d_in[2];
  const float* pre_g0    = (const float*)d_in[3];
  const float* pre_b0    = (const float*)d_in[4];
  const float* pre_w1    = (const float*)d_in[5];
  const float* pre_g1    = (const float*)d_in[6];
  const float* pre_b1    = (const float*)d_in[7];
  const float* pre_w2    = (const float*)d_in[8];
  const float* pre_bias2 = (const float*)d_in[9];
  const float* mlp_w0    = (const float*)d_in[10];
  const float* mlp_g0    = (const float*)d_in[11];
  const float* mlp_b0    = (const float*)d_in[12];
  const float* mlp_w1    = (const float*)d_in[13];
  const float* mlp_g1    = (const float*)d_in[14];
  const float* mlp_b1    = (const float*)d_in[15];
  const float* mlp_w2    = (const float*)d_in[16];
  const float* mlp_bias2 = (const float*)d_in[17];
  const float* out_w0    = (const float*)d_in[18];
  const float* out_b0    = (const float*)d_in[19];
  const float* out_w1    = (const float*)d_in[20];
  const float* out_b1    = (const float*)d_in[21];

  bf16* ws = (bf16*)d_ws;   // 1,064,960 B of ws used

  (void)hipFuncSetAttribute((const void*)&traj_kernel,
                            hipFuncAttributeMaxDynamicSharedMemorySize, LDS_TOTAL);

  prep_kernel<<<dim3(64, 8), dim3(256), 0, stream>>>(
      pre_w0, pre_w1, pre_w2, mlp_w0, mlp_w1, mlp_w2, out_w0, out_w1, ws);

  traj_kernel<<<dim3(1024), dim3(320), LDS_TOTAL, stream>>>(
      poly, maskp,
      pre_g0, pre_b0, pre_g1, pre_b1, pre_bias2,
      mlp_g0, mlp_b0, mlp_g1, mlp_b1, mlp_bias2,
      out_b0, out_b1,
      ws, (float*)d_out);
}